// Round 9
// baseline (517.410 us; speedup 1.0000x reference)
//
#include <hip/hip_runtime.h>
#include <hip/hip_bf16.h>
#include <hip/hip_fp16.h>

#define N_NODES 50000
#define N_EDGES 800000
#define N_PATHS 3
#define IN_F    128
#define HO      256   // H*OUT
#define N_HEADS 4
#define HID     128

#define BLK_PER_PATH 32
#define EDGES_PER_HB 25000                      // N_EDGES / BLK_PER_PATH
#define HIST_BLOCKS  (N_PATHS * BLK_PER_PATH)   // 96
#define NPACK        12500                      // N_NODES/4 packed u32
#define FEAT_RB      782                        // ceil(50000/64)
#define SCAT_BLOCKS  2344                       // 2.4M edges / (256*4)
#define FEAT_ELEMS   ((size_t)N_NODES * HO)

typedef __bf16 bf16;
typedef __bf16 bf16x8 __attribute__((ext_vector_type(8)));
typedef float  f32x4  __attribute__((ext_vector_type(4)));
typedef unsigned short u16;
typedef unsigned char  u8;
typedef unsigned int   u32;

// ---- prep: fcwT[p][col][k] bf16 + w1T[col][k] bf16 -------------------------
__global__ __launch_bounds__(256) void k_prep(const float* __restrict__ fc_w,
                                              const float* __restrict__ w1,
                                              bf16* __restrict__ fcwT,
                                              bf16* __restrict__ w1T) {
    int g = blockIdx.x * 256 + threadIdx.x;
    if (g < N_PATHS * IN_F * HO) {                   // 98304: fc_w transpose
        int p = g >> 15, r = g & 32767;
        int col = r & 255, k = r >> 8;
        fcwT[(size_t)p * 32768 + col * IN_F + k] = (bf16)fc_w[(size_t)p * 32768 + k * HO + col];
    } else {
        int gg = g - N_PATHS * IN_F * HO;            // 32768: w1 transpose
        if (gg < HO * HID) {
            int k = gg & 255, j = gg >> 8;           // j: col 0..127, k: 0..255
            w1T[(size_t)j * HO + k] = (bf16)w1[(size_t)k * HID + j];
        }
    }
}

// ---- hist role: LDS histogram (4x u8 packed) + per-edge local rank ---------
__device__ __forceinline__ void hist_role(int b, const int* __restrict__ edges,
                                          u32* __restrict__ cnt32, u8* __restrict__ lrank,
                                          u32* hist) {
    const int p = b / BLK_PER_PATH, blk = b - p * BLK_PER_PATH;
    const int t = threadIdx.x;
    for (int i = t; i < NPACK; i += 256) hist[i] = 0;
    __syncthreads();

    const int* dstp = edges + (size_t)p * 2 * N_EDGES + N_EDGES + blk * EDGES_PER_HB;
    u8* lr = lrank + (size_t)p * N_EDGES + blk * EDGES_PER_HB;
    for (int q = t; q < EDGES_PER_HB / 4; q += 256) {
        int4 d4 = ((const int4*)dstp)[q];
        u32 o0 = atomicAdd(&hist[d4.x >> 2], 1u << ((d4.x & 3) * 8));
        u32 o1 = atomicAdd(&hist[d4.y >> 2], 1u << ((d4.y & 3) * 8));
        u32 o2 = atomicAdd(&hist[d4.z >> 2], 1u << ((d4.z & 3) * 8));
        u32 o3 = atomicAdd(&hist[d4.w >> 2], 1u << ((d4.w & 3) * 8));
        uchar4 r4;
        r4.x = (u8)(o0 >> ((d4.x & 3) * 8));
        r4.y = (u8)(o1 >> ((d4.y & 3) * 8));
        r4.z = (u8)(o2 >> ((d4.z & 3) * 8));
        r4.w = (u8)(o3 >> ((d4.w & 3) * 8));
        ((uchar4*)lr)[q] = r4;
    }
    __syncthreads();
    u32* out = cnt32 + (size_t)b * NPACK;
    for (int i = t; i < NPACK; i += 256) out[i] = hist[i];
}

// ---- fat feat role: one 64-row block does all 3 paths x 2 col-halves -------
__device__ __forceinline__ void feat_role(int rb, const float* __restrict__ h,
                                          const bf16* __restrict__ fcwT,
                                          const float* __restrict__ al,
                                          const float* __restrict__ ar,
                                          __half* __restrict__ featAll,
                                          float* __restrict__ elAll,
                                          float* __restrict__ erAll) {
    const int t = threadIdx.x, w = t >> 6, l = t & 63, lo = l & 15, hi = l >> 4;
    const int arow = rb * 64 + w * 16 + lo;
    const int crow = rb * 64 + w * 16 + hi * 4;

    bf16x8 afr[4];
    if (arow < N_NODES) {
        const float* hp = h + (size_t)arow * IN_F;
#pragma unroll
        for (int ks = 0; ks < 4; ++ks) {
            float4 f0 = *(const float4*)(hp + ks * 32 + hi * 8);
            float4 f1 = *(const float4*)(hp + ks * 32 + hi * 8 + 4);
            bf16x8 a;
            a[0]=(bf16)f0.x; a[1]=(bf16)f0.y; a[2]=(bf16)f0.z; a[3]=(bf16)f0.w;
            a[4]=(bf16)f1.x; a[5]=(bf16)f1.y; a[6]=(bf16)f1.z; a[7]=(bf16)f1.w;
            afr[ks] = a;
        }
    } else {
#pragma unroll
        for (int ks = 0; ks < 4; ++ks) { bf16x8 a = {}; afr[ks] = a; }
    }

    for (int p = 0; p < N_PATHS; ++p) {
        __half* feat = featAll + (size_t)p * FEAT_ELEMS;
        const float* alp = al + p * HO;
        const float* arp = ar + p * HO;
        float* elA = elAll + (size_t)p * N_NODES * 4;
        float* erA = erAll + (size_t)p * N_NODES * 4;
#pragma unroll
        for (int ch = 0; ch < 2; ++ch) {
            const bf16* W = fcwT + (size_t)p * 32768 + (size_t)ch * 128 * IN_F;
            f32x4 acc[8];
#pragma unroll
            for (int c = 0; c < 8; ++c) { f32x4 zz = {0.f,0.f,0.f,0.f}; acc[c] = zz; }
#pragma unroll
            for (int ctl = 0; ctl < 8; ++ctl) {
                const bf16* wp = W + (size_t)(ctl * 16 + lo) * IN_F + hi * 8;
                f32x4 a = acc[ctl];
#pragma unroll
                for (int ks = 0; ks < 4; ++ks)
                    a = __builtin_amdgcn_mfma_f32_16x16x32_bf16(afr[ks], *(const bf16x8*)(wp + ks * 32), a, 0, 0, 0);
                acc[ctl] = a;
            }
            float elP[2][4] = {{0}}, erP[2][4] = {{0}};
#pragma unroll
            for (int ctl = 0; ctl < 8; ++ctl) {
                const int gcol = ch * 128 + ctl * 16 + lo;
                const float av = alp[gcol], bv = arp[gcol];
                const int hl = ctl >> 2;
#pragma unroll
                for (int rr = 0; rr < 4; ++rr) {
                    float v = acc[ctl][rr];
                    elP[hl][rr] = fmaf(v, av, elP[hl][rr]);
                    erP[hl][rr] = fmaf(v, bv, erP[hl][rr]);
                    if (crow + rr < N_NODES)
                        feat[(size_t)(crow + rr) * HO + gcol] = __float2half(v);
                }
            }
#pragma unroll
            for (int hl = 0; hl < 2; ++hl)
#pragma unroll
                for (int rr = 0; rr < 4; ++rr) {
                    float v = elP[hl][rr], u = erP[hl][rr];
#pragma unroll
                    for (int m = 1; m <= 8; m <<= 1) {
                        v += __shfl_xor(v, m, 64);
                        u += __shfl_xor(u, m, 64);
                    }
                    elP[hl][rr] = v; erP[hl][rr] = u;
                }
            if (lo == 0) {
#pragma unroll
                for (int rr = 0; rr < 4; ++rr) {
                    if (crow + rr < N_NODES) {
                        *(float2*)&elA[(crow + rr) * 4 + ch * 2] = make_float2(elP[0][rr], elP[1][rr]);
                        *(float2*)&erA[(crow + rr) * 4 + ch * 2] = make_float2(erP[0][rr], erP[1][rr]);
                    }
                }
            }
        }
    }
}

// ---- fused: hist (LDS atomics) CONCURRENT with MFMA feat -------------------
__global__ __launch_bounds__(256) void k_hf(const int* __restrict__ edges,
                                            u32* __restrict__ cnt32,
                                            u8* __restrict__ lrank,
                                            const float* __restrict__ h,
                                            const bf16* __restrict__ fcwT,
                                            const float* __restrict__ al,
                                            const float* __restrict__ ar,
                                            __half* __restrict__ featAll,
                                            float* __restrict__ elAll,
                                            float* __restrict__ erAll) {
    __shared__ u32 hist[NPACK];                      // 50 KB
    const int bid = blockIdx.x;
    if (bid < HIST_BLOCKS)
        hist_role(bid, edges, cnt32, lrank, hist);
    else
        feat_role(bid - HIST_BLOCKS, h, fcwT, al, ar, featAll, elAll, erAll);
}

// ---- base: per-node prefix over the 32 block counts (in place) + deg -------
__global__ __launch_bounds__(256) void k_base(u32* __restrict__ cnt32,
                                              int* __restrict__ deg) {
    int g = blockIdx.x * 256 + threadIdx.x;
    if (g >= N_PATHS * NPACK) return;
    int p = g / NPACK, q = g - p * NPACK;
    u32 s0 = 0, s1 = 0, s2 = 0, s3 = 0;
#pragma unroll
    for (int blk = 0; blk < BLK_PER_PATH; ++blk) {
        size_t idx = (size_t)(p * BLK_PER_PATH + blk) * NPACK + q;
        u32 c = cnt32[idx];
        cnt32[idx] = s0 | (s1 << 8) | (s2 << 16) | (s3 << 24);
        s0 += c & 0xff; s1 += (c >> 8) & 0xff; s2 += (c >> 16) & 0xff; s3 += c >> 24;
    }
    int4 d4 = {(int)s0, (int)s1, (int)s2, (int)s3};
    *(int4*)(deg + (size_t)p * N_NODES + 4 * q) = d4;
}

__global__ __launch_bounds__(1024) void k_scan(const int* __restrict__ deg,
                                               int* __restrict__ rowptr) {
    __shared__ int part[1024];
    const int p = blockIdx.x;
    const int* dg = deg + p * N_NODES;
    int* rp = rowptr + p * (N_NODES + 1);

    const int tid = threadIdx.x;
    const int CH = (N_NODES + 1023) / 1024;       // 49
    const int start = tid * CH;
    int s = 0;
    for (int i = 0; i < CH; ++i) { int idx = start + i; if (idx < N_NODES) s += dg[idx]; }
    part[tid] = s;
    __syncthreads();
    for (int off = 1; off < 1024; off <<= 1) {
        int v = (tid >= off) ? part[tid - off] : 0;
        __syncthreads();
        part[tid] += v;
        __syncthreads();
    }
    int excl = (tid == 0) ? 0 : part[tid - 1];
    for (int i = 0; i < CH; ++i) {
        int idx = start + i;
        if (idx < N_NODES) { rp[idx] = excl; excl += dg[idx]; }
    }
    if (tid == 1023) rp[N_NODES] = N_EDGES;
}

// ---- scatter + alpha: atomic-free; writes offs (u32) + alph (uint2) --------
__global__ __launch_bounds__(256) void k_scata(const int* __restrict__ edges,
                                               const u8* __restrict__ lrank,
                                               const u32* __restrict__ cnt32,
                                               const int* __restrict__ rowptr,
                                               const float4* __restrict__ elAll,
                                               const float4* __restrict__ erAll,
                                               u32* __restrict__ offsA,
                                               uint2* __restrict__ alphA) {
    int gt = blockIdx.x * 256 + threadIdx.x;
    if (gt >= (N_PATHS * N_EDGES) / 4) return;
    int base = gt * 4;
    int p = base / N_EDGES, e = base - p * N_EDGES;
    const int blk = e / EDGES_PER_HB;
    const int* ep = edges + (size_t)p * 2 * N_EDGES;
    int4 s4 = *(const int4*)(ep + e);
    int4 d4 = *(const int4*)(ep + N_EDGES + e);
    uchar4 r4 = *(const uchar4*)(lrank + base);
    const int* rp = rowptr + p * (N_NODES + 1);
    const u32* bb = cnt32 + (size_t)(p * BLK_PER_PATH + blk) * NPACK;
    const float4* el4 = elAll + (size_t)p * N_NODES;
    const float4* er4 = erAll + (size_t)p * N_NODES;
    u32*   offs = offsA + (size_t)p * N_EDGES;
    uint2* alph = alphA + (size_t)p * N_EDGES;

    int ss[4] = {s4.x, s4.y, s4.z, s4.w};
    int dd[4] = {d4.x, d4.y, d4.z, d4.w};
    int rr[4] = {r4.x, r4.y, r4.z, r4.w};
#pragma unroll
    for (int j = 0; j < 4; ++j) {
        const int s = ss[j], d = dd[j];
        const int pos = rp[d] + (int)((bb[d >> 2] >> ((d & 3) * 8)) & 0xff) + rr[j];
        float4 a = el4[s], b = er4[d];
        float vx = a.x + b.x, vy = a.y + b.y, vz = a.z + b.z, vw = a.w + b.w;
        vx = (vx >= 0.f) ? vx : 0.2f * vx;
        vy = (vy >= 0.f) ? vy : 0.2f * vy;
        vz = (vz >= 0.f) ? vz : 0.2f * vz;
        vw = (vw >= 0.f) ? vw : 0.2f * vw;
        __half2 h01 = __floats2half2_rn(__expf(vx), __expf(vy));
        __half2 h23 = __floats2half2_rn(__expf(vz), __expf(vw));
        offs[pos] = (u32)(s * HO);
        uint2 av = { __builtin_bit_cast(u32, h01), __builtin_bit_cast(u32, h23) };
        alph[pos] = av;
    }
}

// ---- fused gather + semantic attention + output ----------------------------
// Block = 4 nodes x all 3 paths (wave w -> node nb*4+w). z rows live in LDS.
__global__ __launch_bounds__(256) void k_gsem(const u32* __restrict__ offsAll,
                                              const uint2* __restrict__ alphAll,
                                              const int* __restrict__ rowptrAll,
                                              const __half* __restrict__ featAll,
                                              const bf16* __restrict__ w1T,
                                              const float* __restrict__ b1,
                                              const float* __restrict__ w2,
                                              float* __restrict__ out) {
    __shared__ u32     s_off[4][64];
    __shared__ __half2 s_ad[4][4][66];               // [wave][head][edge], padded
    __shared__ bf16    zs[16][272];                  // 12 z-rows + 4 zero pad
    __shared__ float   psem[4][16];
    __shared__ float   betas[4][3];

    const int nb = blockIdx.x;
    const int t = threadIdx.x, w = t >> 6, l = t & 63;
    const int half = l >> 5, c = l & 31, hh = c >> 3;
    const int n = nb * 4 + w;

    // zero pad rows 12..15 (contiguous 4*272 bf16 = 544 u32)
    for (int i = t; i < 544; i += 256) ((u32*)&zs[12][0])[i] = 0;

    for (int p = 0; p < N_PATHS; ++p) {
        const u32*   offs   = offsAll + (size_t)p * N_EDGES;
        const uint2* alph   = alphAll + (size_t)p * N_EDGES;
        const int*   rowptr = rowptrAll + p * (N_NODES + 1);
        const __half* feat  = featAll + (size_t)p * FEAT_ELEMS;

        const int b0 = rowptr[n], b1e = rowptr[n + 1];

        __half2 acc0 = __float2half2_rn(0.f), acc1 = acc0, acc2 = acc0, acc3 = acc0;
        float4 den = {0.f, 0.f, 0.f, 0.f};

        for (int base = b0; base < b1e; base += 64) {
            const int cnt = min(64, b1e - base);
            if (l < cnt) {                           // coalesced staging (per-wave LDS)
                u32 off = offs[base + l];
                uint2 av = alph[base + l];
                s_off[w][l] = off;
                __half2 h01 = __builtin_bit_cast(__half2, av.x);
                __half2 h23 = __builtin_bit_cast(__half2, av.y);
                float2 f01 = __half22float2(h01);
                float2 f23 = __half22float2(h23);
                den.x += f01.x; den.y += f01.y; den.z += f23.x; den.w += f23.y;
                s_ad[w][0][l] = __half2half2(__low2half(h01));
                s_ad[w][1][l] = __half2half2(__high2half(h01));
                s_ad[w][2][l] = __half2half2(__low2half(h23));
                s_ad[w][3][l] = __half2half2(__high2half(h23));
            }
            int i2 = 0;
            for (; i2 + 4 <= cnt; i2 += 4) {         // 4 edges in flight per wave
                const int e1 = i2 + half, e2 = i2 + 2 + half;
                u32 o1 = s_off[w][e1], o2 = s_off[w][e2];
                __half2 a1 = s_ad[w][hh][e1], a2v = s_ad[w][hh][e2];
                const uint4 u1 = *(const uint4*)(feat + o1 + c * 8);
                const uint4 u2 = *(const uint4*)(feat + o2 + c * 8);
                acc0 = __hfma2(__builtin_bit_cast(__half2, u1.x), a1, acc0);
                acc1 = __hfma2(__builtin_bit_cast(__half2, u1.y), a1, acc1);
                acc2 = __hfma2(__builtin_bit_cast(__half2, u1.z), a1, acc2);
                acc3 = __hfma2(__builtin_bit_cast(__half2, u1.w), a1, acc3);
                acc0 = __hfma2(__builtin_bit_cast(__half2, u2.x), a2v, acc0);
                acc1 = __hfma2(__builtin_bit_cast(__half2, u2.y), a2v, acc1);
                acc2 = __hfma2(__builtin_bit_cast(__half2, u2.z), a2v, acc2);
                acc3 = __hfma2(__builtin_bit_cast(__half2, u2.w), a2v, acc3);
            }
            for (; i2 < cnt; i2 += 2) {              // tail
                const int e = i2 + half;
                if (e < cnt) {
                    u32 o1 = s_off[w][e];
                    __half2 a1 = s_ad[w][hh][e];
                    const uint4 u = *(const uint4*)(feat + o1 + c * 8);
                    acc0 = __hfma2(__builtin_bit_cast(__half2, u.x), a1, acc0);
                    acc1 = __hfma2(__builtin_bit_cast(__half2, u.y), a1, acc1);
                    acc2 = __hfma2(__builtin_bit_cast(__half2, u.z), a1, acc2);
                    acc3 = __hfma2(__builtin_bit_cast(__half2, u.w), a1, acc3);
                }
            }
        }

        float s[8];
        { float2 f0 = __half22float2(acc0), f1 = __half22float2(acc1),
                 f2 = __half22float2(acc2), f3 = __half22float2(acc3);
          s[0]=f0.x; s[1]=f0.y; s[2]=f1.x; s[3]=f1.y; s[4]=f2.x; s[5]=f2.y; s[6]=f3.x; s[7]=f3.y; }
#pragma unroll
        for (int j = 0; j < 8; ++j) s[j] += __shfl_xor(s[j], 32, 64);
#pragma unroll
        for (int off = 32; off; off >>= 1) {
            den.x += __shfl_xor(den.x, off, 64);
            den.y += __shfl_xor(den.y, off, 64);
            den.z += __shfl_xor(den.z, off, 64);
            den.w += __shfl_xor(den.w, off, 64);
        }
        const float d = (hh == 0) ? den.x : (hh == 1) ? den.y : (hh == 2) ? den.z : den.w;
        const float inv = (d > 0.f) ? 1.f / d : 0.f;
        if (half == 0) {
            bf16x8 ov;
#pragma unroll
            for (int j = 0; j < 8; ++j) {
                float v = s[j] * inv;
                v = (v > 0.f) ? v : expm1f(v);       // elu
                ov[j] = (bf16)v;
            }
            *(bf16x8*)&zs[w * 3 + p][c * 8] = ov;
        }
    }
    __syncthreads();

    // semantic attention: [16 x 256] @ w1T -> tanh -> @w2 (MFMA, 16 valid rows=12)
    const int lo = l & 15, hi = l >> 4;
    f32x4 sa0 = {0.f,0.f,0.f,0.f}, sa1 = sa0;
    const int j0 = (2 * w + 0) * 16 + lo;
    const int j1 = (2 * w + 1) * 16 + lo;
    for (int s = 0; s < 8; ++s) {
        bf16x8 a  = *(const bf16x8*)&zs[lo][s * 32 + hi * 8];
        bf16x8 bA = *(const bf16x8*)(w1T + (size_t)j0 * HO + s * 32 + hi * 8);
        bf16x8 bB = *(const bf16x8*)(w1T + (size_t)j1 * HO + s * 32 + hi * 8);
        sa0 = __builtin_amdgcn_mfma_f32_16x16x32_bf16(a, bA, sa0, 0, 0, 0);
        sa1 = __builtin_amdgcn_mfma_f32_16x16x32_bf16(a, bB, sa1, 0, 0, 0);
    }
    const float b1_0 = b1[j0], w2_0 = w2[j0];
    const float b1_1 = b1[j1], w2_1 = w2[j1];
#pragma unroll
    for (int r = 0; r < 4; ++r) {
        float tt = tanhf(sa0[r] + b1_0) * w2_0 + tanhf(sa1[r] + b1_1) * w2_1;
        tt += __shfl_xor(tt, 1, 64);
        tt += __shfl_xor(tt, 2, 64);
        tt += __shfl_xor(tt, 4, 64);
        tt += __shfl_xor(tt, 8, 64);
        if (lo == 0) psem[w][hi * 4 + r] = tt;
    }
    __syncthreads();
    if (t < 4) {
        float a0 = psem[0][3*t+0] + psem[1][3*t+0] + psem[2][3*t+0] + psem[3][3*t+0];
        float a1v = psem[0][3*t+1] + psem[1][3*t+1] + psem[2][3*t+1] + psem[3][3*t+1];
        float a2v = psem[0][3*t+2] + psem[1][3*t+2] + psem[2][3*t+2] + psem[3][3*t+2];
        float mx = fmaxf(a0, fmaxf(a1v, a2v));
        float e0 = __expf(a0 - mx), e1 = __expf(a1v - mx), e2 = __expf(a2v - mx);
        float is = 1.f / (e0 + e1 + e2);
        betas[t][0] = e0 * is; betas[t][1] = e1 * is; betas[t][2] = e2 * is;
    }
    __syncthreads();
#pragma unroll
    for (int i = 0; i < 4; ++i) {
        float o = betas[i][0] * (float)zs[3*i+0][t]
                + betas[i][1] * (float)zs[3*i+1][t]
                + betas[i][2] * (float)zs[3*i+2][t];
        out[(size_t)(nb * 4 + i) * HO + t] = o;
    }
}

// ---------------------------------------------------------------------------
static inline size_t align256(size_t x) { return (x + 255) & ~(size_t)255; }

extern "C" void kernel_launch(void* const* d_in, const int* in_sizes, int n_in,
                              void* d_out, int out_size, void* d_ws, size_t ws_size,
                              hipStream_t stream) {
    const float* h     = (const float*)d_in[0];
    const int*   edges = (const int*)d_in[1];     // [P,2,E]
    const float* fc_w  = (const float*)d_in[2];   // [P,128,256]
    const float* al    = (const float*)d_in[3];   // [P,4,64]
    const float* ar    = (const float*)d_in[4];
    const float* w1    = (const float*)d_in[5];   // [256,128]
    const float* b1    = (const float*)d_in[6];   // [128]
    const float* w2    = (const float*)d_in[7];   // [128]
    float* out = (float*)d_out;

    char* base = (char*)d_ws;
    size_t off = 0;
    auto carve = [&](size_t bytes) -> char* {
        char* p = base + off; off = align256(off + bytes); return p;
    };
    __half* feat   = (__half*)carve((size_t)N_PATHS * FEAT_ELEMS * 2);   // 76.8 MB
    u32*    offsA  = (u32*)carve((size_t)N_PATHS * N_EDGES * 4);         // 9.6 MB
    uint2*  alphA  = (uint2*)carve((size_t)N_PATHS * N_EDGES * 8);       // 19.2 MB
    bf16*   fcwT   = (bf16*)carve((size_t)N_PATHS * IN_F * HO * 2);      // 192 KB
    bf16*   w1T    = (bf16*)carve((size_t)HO * HID * 2);                 // 64 KB
    float*  el     = (float*)carve((size_t)N_PATHS * N_NODES * 4 * 4);   // 2.4 MB
    float*  er     = (float*)carve((size_t)N_PATHS * N_NODES * 4 * 4);   // 2.4 MB
    int*    deg    = (int*)carve((size_t)N_PATHS * N_NODES * 4);         // 0.6 MB
    int*    rowptr = (int*)carve((size_t)N_PATHS * (N_NODES + 1) * 4);   // 0.6 MB
    u8*     lrank  = (u8*)carve((size_t)N_PATHS * N_EDGES);              // 2.4 MB
    u32*    cnt32  = (u32*)carve((size_t)HIST_BLOCKS * NPACK * 4);       // 4.8 MB
    (void)ws_size; (void)in_sizes; (void)n_in; (void)out_size;

    k_prep<<<512, 256, 0, stream>>>(fc_w, w1, fcwT, w1T);
    // hist (LDS atomics, 96 blocks) concurrent with all 3 MFMA feat GEMMs
    k_hf<<<HIST_BLOCKS + FEAT_RB, 256, 0, stream>>>(
        edges, cnt32, lrank, h, fcwT, al, ar, feat, el, er);
    k_base<<<(N_PATHS * NPACK + 255) / 256, 256, 0, stream>>>(cnt32, deg);
    k_scan<<<N_PATHS, 1024, 0, stream>>>(deg, rowptr);
    k_scata<<<SCAT_BLOCKS, 256, 0, stream>>>(
        edges, lrank, cnt32, rowptr, (const float4*)el, (const float4*)er, offsA, alphA);
    // fused gather + semantic attention + output
    k_gsem<<<N_NODES / 4, 256, 0, stream>>>(
        offsA, alphA, rowptr, feat, w1T, b1, w2, out);
}

// Round 10
// 486.871 us; speedup vs baseline: 1.0627x; 1.0627x over previous
//
#include <hip/hip_runtime.h>
#include <hip/hip_bf16.h>
#include <hip/hip_fp16.h>

#define N_NODES 50000
#define N_EDGES 800000
#define N_PATHS 3
#define IN_F    128
#define HO      256   // H*OUT
#define N_HEADS 4
#define HID     128

#define BLK_PER_PATH 32
#define EDGES_PER_HB 25000                      // N_EDGES / BLK_PER_PATH
#define HIST_BLOCKS  (N_PATHS * BLK_PER_PATH)   // 96
#define NPACK        12500                      // N_NODES/4 packed u32
#define FEAT_RB      782                        // ceil(50000/64)
#define SCAT_PP      782                        // ceil(800000/4/256) blocks, one path
#define GATH_PP      12500                      // N_NODES/4 blocks, one path
#define FEAT_ELEMS   ((size_t)N_NODES * HO)

typedef __bf16 bf16;
typedef __bf16 bf16x8 __attribute__((ext_vector_type(8)));
typedef float  f32x4  __attribute__((ext_vector_type(4)));
typedef unsigned short u16;
typedef unsigned char  u8;
typedef unsigned int   u32;

// ---- prep: fcwT[p][col][k] bf16 + w1T[col][k] bf16 -------------------------
__global__ __launch_bounds__(256) void k_prep(const float* __restrict__ fc_w,
                                              const float* __restrict__ w1,
                                              bf16* __restrict__ fcwT,
                                              bf16* __restrict__ w1T) {
    int g = blockIdx.x * 256 + threadIdx.x;
    if (g < N_PATHS * IN_F * HO) {                   // 98304: fc_w transpose
        int p = g >> 15, r = g & 32767;
        int col = r & 255, k = r >> 8;
        fcwT[(size_t)p * 32768 + col * IN_F + k] = (bf16)fc_w[(size_t)p * 32768 + k * HO + col];
    } else {
        int gg = g - N_PATHS * IN_F * HO;            // 32768: w1 transpose
        if (gg < HO * HID) {
            int k = gg & 255, j = gg >> 8;
            w1T[(size_t)j * HO + k] = (bf16)w1[(size_t)k * HID + j];
        }
    }
}

// ---- hist role: LDS histogram (4x u8 packed) + per-edge local rank ---------
__device__ __forceinline__ void hist_role(int b, const int* __restrict__ edges,
                                          u32* __restrict__ cnt32, u8* __restrict__ lrank,
                                          u32* hist) {
    const int p = b / BLK_PER_PATH, blk = b - p * BLK_PER_PATH;
    const int t = threadIdx.x;
    for (int i = t; i < NPACK; i += 256) hist[i] = 0;
    __syncthreads();

    const int* dstp = edges + (size_t)p * 2 * N_EDGES + N_EDGES + blk * EDGES_PER_HB;
    u8* lr = lrank + (size_t)p * N_EDGES + blk * EDGES_PER_HB;
    for (int q = t; q < EDGES_PER_HB / 4; q += 256) {
        int4 d4 = ((const int4*)dstp)[q];
        u32 o0 = atomicAdd(&hist[d4.x >> 2], 1u << ((d4.x & 3) * 8));
        u32 o1 = atomicAdd(&hist[d4.y >> 2], 1u << ((d4.y & 3) * 8));
        u32 o2 = atomicAdd(&hist[d4.z >> 2], 1u << ((d4.z & 3) * 8));
        u32 o3 = atomicAdd(&hist[d4.w >> 2], 1u << ((d4.w & 3) * 8));
        uchar4 r4;
        r4.x = (u8)(o0 >> ((d4.x & 3) * 8));
        r4.y = (u8)(o1 >> ((d4.y & 3) * 8));
        r4.z = (u8)(o2 >> ((d4.z & 3) * 8));
        r4.w = (u8)(o3 >> ((d4.w & 3) * 8));
        ((uchar4*)lr)[q] = r4;
    }
    __syncthreads();
    u32* out = cnt32 + (size_t)b * NPACK;
    for (int i = t; i < NPACK; i += 256) out[i] = hist[i];
}

// ---- fat feat role: one 64-row block does all 3 paths x 2 col-halves -------
__device__ __forceinline__ void feat_role(int rb, const float* __restrict__ h,
                                          const bf16* __restrict__ fcwT,
                                          const float* __restrict__ al,
                                          const float* __restrict__ ar,
                                          __half* __restrict__ featAll,
                                          float* __restrict__ elAll,
                                          float* __restrict__ erAll) {
    const int t = threadIdx.x, w = t >> 6, l = t & 63, lo = l & 15, hi = l >> 4;
    const int arow = rb * 64 + w * 16 + lo;
    const int crow = rb * 64 + w * 16 + hi * 4;

    bf16x8 afr[4];
    if (arow < N_NODES) {
        const float* hp = h + (size_t)arow * IN_F;
#pragma unroll
        for (int ks = 0; ks < 4; ++ks) {
            float4 f0 = *(const float4*)(hp + ks * 32 + hi * 8);
            float4 f1 = *(const float4*)(hp + ks * 32 + hi * 8 + 4);
            bf16x8 a;
            a[0]=(bf16)f0.x; a[1]=(bf16)f0.y; a[2]=(bf16)f0.z; a[3]=(bf16)f0.w;
            a[4]=(bf16)f1.x; a[5]=(bf16)f1.y; a[6]=(bf16)f1.z; a[7]=(bf16)f1.w;
            afr[ks] = a;
        }
    } else {
#pragma unroll
        for (int ks = 0; ks < 4; ++ks) { bf16x8 a = {}; afr[ks] = a; }
    }

    for (int p = 0; p < N_PATHS; ++p) {
        __half* feat = featAll + (size_t)p * FEAT_ELEMS;
        const float* alp = al + p * HO;
        const float* arp = ar + p * HO;
        float* elA = elAll + (size_t)p * N_NODES * 4;
        float* erA = erAll + (size_t)p * N_NODES * 4;
#pragma unroll
        for (int ch = 0; ch < 2; ++ch) {
            const bf16* W = fcwT + (size_t)p * 32768 + (size_t)ch * 128 * IN_F;
            f32x4 acc[8];
#pragma unroll
            for (int c = 0; c < 8; ++c) { f32x4 zz = {0.f,0.f,0.f,0.f}; acc[c] = zz; }
#pragma unroll
            for (int ctl = 0; ctl < 8; ++ctl) {
                const bf16* wp = W + (size_t)(ctl * 16 + lo) * IN_F + hi * 8;
                f32x4 a = acc[ctl];
#pragma unroll
                for (int ks = 0; ks < 4; ++ks)
                    a = __builtin_amdgcn_mfma_f32_16x16x32_bf16(afr[ks], *(const bf16x8*)(wp + ks * 32), a, 0, 0, 0);
                acc[ctl] = a;
            }
            float elP[2][4] = {{0}}, erP[2][4] = {{0}};
#pragma unroll
            for (int ctl = 0; ctl < 8; ++ctl) {
                const int gcol = ch * 128 + ctl * 16 + lo;
                const float av = alp[gcol], bv = arp[gcol];
                const int hl = ctl >> 2;
#pragma unroll
                for (int rr = 0; rr < 4; ++rr) {
                    float v = acc[ctl][rr];
                    elP[hl][rr] = fmaf(v, av, elP[hl][rr]);
                    erP[hl][rr] = fmaf(v, bv, erP[hl][rr]);
                    if (crow + rr < N_NODES)
                        feat[(size_t)(crow + rr) * HO + gcol] = __float2half(v);
                }
            }
#pragma unroll
            for (int hl = 0; hl < 2; ++hl)
#pragma unroll
                for (int rr = 0; rr < 4; ++rr) {
                    float v = elP[hl][rr], u = erP[hl][rr];
#pragma unroll
                    for (int m = 1; m <= 8; m <<= 1) {
                        v += __shfl_xor(v, m, 64);
                        u += __shfl_xor(u, m, 64);
                    }
                    elP[hl][rr] = v; erP[hl][rr] = u;
                }
            if (lo == 0) {
#pragma unroll
                for (int rr = 0; rr < 4; ++rr) {
                    if (crow + rr < N_NODES) {
                        *(float2*)&elA[(crow + rr) * 4 + ch * 2] = make_float2(elP[0][rr], elP[1][rr]);
                        *(float2*)&erA[(crow + rr) * 4 + ch * 2] = make_float2(erP[0][rr], erP[1][rr]);
                    }
                }
            }
        }
    }
}

// ---- fused: hist (LDS atomics) CONCURRENT with MFMA feat -------------------
__global__ __launch_bounds__(256) void k_hf(const int* __restrict__ edges,
                                            u32* __restrict__ cnt32,
                                            u8* __restrict__ lrank,
                                            const float* __restrict__ h,
                                            const bf16* __restrict__ fcwT,
                                            const float* __restrict__ al,
                                            const float* __restrict__ ar,
                                            __half* __restrict__ featAll,
                                            float* __restrict__ elAll,
                                            float* __restrict__ erAll) {
    __shared__ u32 hist[NPACK];                      // 50 KB
    const int bid = blockIdx.x;
    if (bid < HIST_BLOCKS)
        hist_role(bid, edges, cnt32, lrank, hist);
    else
        feat_role(bid - HIST_BLOCKS, h, fcwT, al, ar, featAll, elAll, erAll);
}

// ---- base: per-node prefix over the 32 block counts (in place) + deg -------
__global__ __launch_bounds__(256) void k_base(u32* __restrict__ cnt32,
                                              int* __restrict__ deg) {
    int g = blockIdx.x * 256 + threadIdx.x;
    if (g >= N_PATHS * NPACK) return;
    int p = g / NPACK, q = g - p * NPACK;
    u32 s0 = 0, s1 = 0, s2 = 0, s3 = 0;
#pragma unroll
    for (int blk = 0; blk < BLK_PER_PATH; ++blk) {
        size_t idx = (size_t)(p * BLK_PER_PATH + blk) * NPACK + q;
        u32 c = cnt32[idx];
        cnt32[idx] = s0 | (s1 << 8) | (s2 << 16) | (s3 << 24);
        s0 += c & 0xff; s1 += (c >> 8) & 0xff; s2 += (c >> 16) & 0xff; s3 += c >> 24;
    }
    int4 d4 = {(int)s0, (int)s1, (int)s2, (int)s3};
    *(int4*)(deg + (size_t)p * N_NODES + 4 * q) = d4;
}

__global__ __launch_bounds__(1024) void k_scan(const int* __restrict__ deg,
                                               int* __restrict__ rowptr) {
    __shared__ int part[1024];
    const int p = blockIdx.x;
    const int* dg = deg + p * N_NODES;
    int* rp = rowptr + p * (N_NODES + 1);

    const int tid = threadIdx.x;
    const int CH = (N_NODES + 1023) / 1024;       // 49
    const int start = tid * CH;
    int s = 0;
    for (int i = 0; i < CH; ++i) { int idx = start + i; if (idx < N_NODES) s += dg[idx]; }
    part[tid] = s;
    __syncthreads();
    for (int off = 1; off < 1024; off <<= 1) {
        int v = (tid >= off) ? part[tid - off] : 0;
        __syncthreads();
        part[tid] += v;
        __syncthreads();
    }
    int excl = (tid == 0) ? 0 : part[tid - 1];
    for (int i = 0; i < CH; ++i) {
        int idx = start + i;
        if (idx < N_NODES) { rp[idx] = excl; excl += dg[idx]; }
    }
    if (tid == 1023) rp[N_NODES] = N_EDGES;
}

// ---- scatter role (one path): atomic-free, writes u16 src csr --------------
__device__ __forceinline__ void scatter_role(int b, int p, const int* __restrict__ edges,
                                             const u8* __restrict__ lrank,
                                             const u32* __restrict__ cnt32,
                                             const int* __restrict__ rowptr,
                                             u16* __restrict__ csrAll) {
    int e = (b * 256 + threadIdx.x) * 4;
    if (e >= N_EDGES) return;
    const int blk = e / EDGES_PER_HB;                // quad never crosses chunk
    const int* ep = edges + (size_t)p * 2 * N_EDGES;
    int4 s4 = *(const int4*)(ep + e);
    int4 d4 = *(const int4*)(ep + N_EDGES + e);
    uchar4 r4 = *(const uchar4*)(lrank + (size_t)p * N_EDGES + e);
    const int* rp = rowptr + p * (N_NODES + 1);
    const u32* bb = cnt32 + (size_t)(p * BLK_PER_PATH + blk) * NPACK;
    u16* c = csrAll + (size_t)p * N_EDGES;
    int p0 = rp[d4.x] + (int)((bb[d4.x >> 2] >> ((d4.x & 3) * 8)) & 0xff) + r4.x;
    int p1 = rp[d4.y] + (int)((bb[d4.y >> 2] >> ((d4.y & 3) * 8)) & 0xff) + r4.y;
    int p2 = rp[d4.z] + (int)((bb[d4.z >> 2] >> ((d4.z & 3) * 8)) & 0xff) + r4.z;
    int p3 = rp[d4.w] + (int)((bb[d4.w >> 2] >> ((d4.w & 3) * 8)) & 0xff) + r4.w;
    c[p0] = (u16)s4.x; c[p1] = (u16)s4.y; c[p2] = (u16)s4.z; c[p3] = (u16)s4.w;
}

// ---- gather role (one path): wave/node, alpha inline, unroll-4 -------------
__device__ __forceinline__ void gather_role(int nb, int p,
                                            const u16* __restrict__ csrAll,
                                            const int* __restrict__ rowptrAll,
                                            const float4* __restrict__ elAll,
                                            const float4* __restrict__ erAll,
                                            const __half* __restrict__ featAll,
                                            bf16* __restrict__ z,
                                            u32 (*s_off)[64], __half2 (*s_ad)[4][66]) {
    const int t = threadIdx.x, w = t >> 6, l = t & 63;
    const int half = l >> 5, c = l & 31, hh = c >> 3;
    const int n = nb * 4 + w;

    const u16*    csr    = csrAll + (size_t)p * N_EDGES;
    const int*    rowptr = rowptrAll + p * (N_NODES + 1);
    const float4* el4    = elAll + (size_t)p * N_NODES;
    const __half* feat   = featAll + (size_t)p * FEAT_ELEMS;

    const int b0 = rowptr[n], b1e = rowptr[n + 1];
    const float4 er_n = (erAll + (size_t)p * N_NODES)[n];

    __half2 acc0 = __float2half2_rn(0.f), acc1 = acc0, acc2 = acc0, acc3 = acc0;
    float4 den = {0.f, 0.f, 0.f, 0.f};

    for (int base = b0; base < b1e; base += 64) {
        const int cnt = min(64, b1e - base);
        if (l < cnt) {                               // staging: 2B csr + L2 el read
            int sv = csr[base + l];
            s_off[w][l] = (u32)(sv * HO);
            float4 e = el4[sv];
            float vx = e.x + er_n.x, vy = e.y + er_n.y,
                  vz = e.z + er_n.z, vw = e.w + er_n.w;
            vx = (vx >= 0.f) ? vx : 0.2f * vx;
            vy = (vy >= 0.f) ? vy : 0.2f * vy;
            vz = (vz >= 0.f) ? vz : 0.2f * vz;
            vw = (vw >= 0.f) ? vw : 0.2f * vw;
            float ex = __expf(vx), ey = __expf(vy), ez = __expf(vz), ew = __expf(vw);
            den.x += ex; den.y += ey; den.z += ez; den.w += ew;
            s_ad[w][0][l] = __float2half2_rn(ex);
            s_ad[w][1][l] = __float2half2_rn(ey);
            s_ad[w][2][l] = __float2half2_rn(ez);
            s_ad[w][3][l] = __float2half2_rn(ew);
        }
        int i2 = 0;
        for (; i2 + 4 <= cnt; i2 += 4) {             // 2 loads in flight per lane
            const int e1 = i2 + half, e2 = i2 + 2 + half;
            u32 o1 = s_off[w][e1], o2 = s_off[w][e2];
            __half2 a1 = s_ad[w][hh][e1], a2v = s_ad[w][hh][e2];
            const uint4 u1 = *(const uint4*)(feat + o1 + c * 8);
            const uint4 u2 = *(const uint4*)(feat + o2 + c * 8);
            acc0 = __hfma2(__builtin_bit_cast(__half2, u1.x), a1, acc0);
            acc1 = __hfma2(__builtin_bit_cast(__half2, u1.y), a1, acc1);
            acc2 = __hfma2(__builtin_bit_cast(__half2, u1.z), a1, acc2);
            acc3 = __hfma2(__builtin_bit_cast(__half2, u1.w), a1, acc3);
            acc0 = __hfma2(__builtin_bit_cast(__half2, u2.x), a2v, acc0);
            acc1 = __hfma2(__builtin_bit_cast(__half2, u2.y), a2v, acc1);
            acc2 = __hfma2(__builtin_bit_cast(__half2, u2.z), a2v, acc2);
            acc3 = __hfma2(__builtin_bit_cast(__half2, u2.w), a2v, acc3);
        }
        for (; i2 < cnt; i2 += 2) {                  // tail
            const int e = i2 + half;
            if (e < cnt) {
                u32 o1 = s_off[w][e];
                __half2 a1 = s_ad[w][hh][e];
                const uint4 u = *(const uint4*)(feat + o1 + c * 8);
                acc0 = __hfma2(__builtin_bit_cast(__half2, u.x), a1, acc0);
                acc1 = __hfma2(__builtin_bit_cast(__half2, u.y), a1, acc1);
                acc2 = __hfma2(__builtin_bit_cast(__half2, u.z), a1, acc2);
                acc3 = __hfma2(__builtin_bit_cast(__half2, u.w), a1, acc3);
            }
        }
    }

    float s[8];
    { float2 f0 = __half22float2(acc0), f1 = __half22float2(acc1),
             f2 = __half22float2(acc2), f3 = __half22float2(acc3);
      s[0]=f0.x; s[1]=f0.y; s[2]=f1.x; s[3]=f1.y; s[4]=f2.x; s[5]=f2.y; s[6]=f3.x; s[7]=f3.y; }
#pragma unroll
    for (int j = 0; j < 8; ++j) s[j] += __shfl_xor(s[j], 32, 64);
#pragma unroll
    for (int off = 32; off; off >>= 1) {
        den.x += __shfl_xor(den.x, off, 64);
        den.y += __shfl_xor(den.y, off, 64);
        den.z += __shfl_xor(den.z, off, 64);
        den.w += __shfl_xor(den.w, off, 64);
    }
    const float d = (hh == 0) ? den.x : (hh == 1) ? den.y : (hh == 2) ? den.z : den.w;
    const float inv = (d > 0.f) ? 1.f / d : 0.f;
    if (half == 0) {
        bf16x8 ov;
#pragma unroll
        for (int j = 0; j < 8; ++j) {
            float v = s[j] * inv;
            v = (v > 0.f) ? v : expm1f(v);           // elu
            ov[j] = (bf16)v;
        }
        *(bf16x8*)(z + (size_t)n * (N_PATHS * HO) + p * HO + c * 8) = ov;
    }
}

// ---- pipelined: scatter(sp) blocks first, then gather(gp) blocks -----------
__global__ __launch_bounds__(256) void k_gs(int gp, int sp,
                                            const int* __restrict__ edges,
                                            const u8* __restrict__ lrank,
                                            const u32* __restrict__ cnt32,
                                            const int* __restrict__ rowptr,
                                            u16* __restrict__ csr,
                                            const float4* __restrict__ el,
                                            const float4* __restrict__ er,
                                            const __half* __restrict__ feat,
                                            bf16* __restrict__ z) {
    __shared__ u32     s_off[4][64];
    __shared__ __half2 s_ad[4][4][66];
    const int bid = blockIdx.x;
    if (bid < SCAT_PP) {
        if (sp >= 0) scatter_role(bid, sp, edges, lrank, cnt32, rowptr, csr);
    } else if (gp >= 0) {
        gather_role(bid - SCAT_PP, gp, csr, rowptr, el, er, feat, z, s_off, s_ad);
    }
}

// ---- semantic attention + output: bf16 LDS, MFMA logits (16 nodes/block) ---
__global__ __launch_bounds__(256) void k_semout(const bf16* __restrict__ z,
                                                const bf16* __restrict__ w1T,
                                                const float* __restrict__ b1,
                                                const float* __restrict__ w2,
                                                float* __restrict__ out) {
    __shared__ bf16  zs[48 * 264];
    __shared__ float psem[4][48];
    __shared__ float betas[16][4];

    const int t = threadIdx.x, w = t >> 6, l = t & 63;
    const int lo = l & 15, hi = l >> 4;
    const int n0 = blockIdx.x * 16;

    // B-frag preload from pre-transposed bf16 w1T
    bf16x8 bfr[2][8];
#pragma unroll
    for (int ct = 0; ct < 2; ++ct) {
        const int j = (2 * w + ct) * 16 + lo;
#pragma unroll
        for (int s = 0; s < 8; ++s)
            bfr[ct][s] = *(const bf16x8*)(w1T + (size_t)j * HO + s * 32 + hi * 8);
    }

    const uint4* zg4 = (const uint4*)(z + (size_t)n0 * (N_PATHS * HO));
    for (int i = t; i < 1536; i += 256) {
        uint4 v = zg4[i];
        int r = i >> 5, cin = (i & 31) * 8;
        *(uint4*)&zs[r * 264 + cin] = v;
    }
    __syncthreads();

    f32x4 acc[2][3];
#pragma unroll
    for (int ct = 0; ct < 2; ++ct)
#pragma unroll
        for (int m = 0; m < 3; ++m) { f32x4 zz = {0.f,0.f,0.f,0.f}; acc[ct][m] = zz; }

    for (int s = 0; s < 8; ++s) {
#pragma unroll
        for (int m = 0; m < 3; ++m) {
            bf16x8 a = *(const bf16x8*)&zs[(m * 16 + lo) * 264 + s * 32 + hi * 8];
            acc[0][m] = __builtin_amdgcn_mfma_f32_16x16x32_bf16(a, bfr[0][s], acc[0][m], 0, 0, 0);
            acc[1][m] = __builtin_amdgcn_mfma_f32_16x16x32_bf16(a, bfr[1][s], acc[1][m], 0, 0, 0);
        }
    }

    const int j0 = (2 * w + 0) * 16 + lo;
    const int j1 = (2 * w + 1) * 16 + lo;
    const float b1_0 = b1[j0], w2_0 = w2[j0];
    const float b1_1 = b1[j1], w2_1 = w2[j1];
#pragma unroll
    for (int m = 0; m < 3; ++m) {
#pragma unroll
        for (int r = 0; r < 4; ++r) {
            float tt = tanhf(acc[0][m][r] + b1_0) * w2_0
                     + tanhf(acc[1][m][r] + b1_1) * w2_1;
            tt += __shfl_xor(tt, 1, 64);
            tt += __shfl_xor(tt, 2, 64);
            tt += __shfl_xor(tt, 4, 64);
            tt += __shfl_xor(tt, 8, 64);
            if (lo == 0) psem[w][m * 16 + hi * 4 + r] = tt;
        }
    }
    __syncthreads();
    if (t < 48) psem[0][t] = psem[0][t] + psem[1][t] + psem[2][t] + psem[3][t];
    __syncthreads();
    if (t < 16) {
        float a0 = psem[0][3 * t], a1 = psem[0][3 * t + 1], a2 = psem[0][3 * t + 2];
        float mx = fmaxf(a0, fmaxf(a1, a2));
        float e0 = __expf(a0 - mx), e1 = __expf(a1 - mx), e2 = __expf(a2 - mx);
        float is = 1.f / (e0 + e1 + e2);
        betas[t][0] = e0 * is; betas[t][1] = e1 * is; betas[t][2] = e2 * is;
    }
    __syncthreads();
    for (int i = 0; i < 16; ++i) {
        float bb0 = betas[i][0], bb1 = betas[i][1], bb2 = betas[i][2];
        float o = bb0 * (float)zs[(3 * i + 0) * 264 + t]
                + bb1 * (float)zs[(3 * i + 1) * 264 + t]
                + bb2 * (float)zs[(3 * i + 2) * 264 + t];
        out[(size_t)(n0 + i) * HO + t] = o;
    }
}

// ---------------------------------------------------------------------------
static inline size_t align256(size_t x) { return (x + 255) & ~(size_t)255; }

extern "C" void kernel_launch(void* const* d_in, const int* in_sizes, int n_in,
                              void* d_out, int out_size, void* d_ws, size_t ws_size,
                              hipStream_t stream) {
    const float* h     = (const float*)d_in[0];
    const int*   edges = (const int*)d_in[1];     // [P,2,E]
    const float* fc_w  = (const float*)d_in[2];   // [P,128,256]
    const float* al    = (const float*)d_in[3];   // [P,4,64]
    const float* ar    = (const float*)d_in[4];
    const float* w1    = (const float*)d_in[5];   // [256,128]
    const float* b1    = (const float*)d_in[6];   // [128]
    const float* w2    = (const float*)d_in[7];   // [128]
    float* out = (float*)d_out;

    char* base = (char*)d_ws;
    size_t off = 0;
    auto carve = [&](size_t bytes) -> char* {
        char* p = base + off; off = align256(off + bytes); return p;
    };
    __half* feat   = (__half*)carve((size_t)N_PATHS * FEAT_ELEMS * 2);   // 76.8 MB
    bf16*   zbuf   = (bf16*)carve((size_t)N_NODES * N_PATHS * HO * 2);   // 76.8 MB
    u16*    csr    = (u16*)carve((size_t)N_PATHS * N_EDGES * 2);         // 4.8 MB
    bf16*   fcwT   = (bf16*)carve((size_t)N_PATHS * IN_F * HO * 2);      // 192 KB
    bf16*   w1T    = (bf16*)carve((size_t)HO * HID * 2);                 // 64 KB
    float*  el     = (float*)carve((size_t)N_PATHS * N_NODES * 4 * 4);   // 2.4 MB
    float*  er     = (float*)carve((size_t)N_PATHS * N_NODES * 4 * 4);   // 2.4 MB
    int*    deg    = (int*)carve((size_t)N_PATHS * N_NODES * 4);         // 0.6 MB
    int*    rowptr = (int*)carve((size_t)N_PATHS * (N_NODES + 1) * 4);   // 0.6 MB
    u8*     lrank  = (u8*)carve((size_t)N_PATHS * N_EDGES);              // 2.4 MB
    u32*    cnt32  = (u32*)carve((size_t)HIST_BLOCKS * NPACK * 4);       // 4.8 MB
    (void)ws_size; (void)in_sizes; (void)n_in; (void)out_size;

    k_prep<<<512, 256, 0, stream>>>(fc_w, w1, fcwT, w1T);
    // hist (LDS atomics, 96 blocks) concurrent with all 3 MFMA feat GEMMs
    k_hf<<<HIST_BLOCKS + FEAT_RB, 256, 0, stream>>>(
        edges, cnt32, lrank, h, fcwT, al, ar, feat, el, er);
    k_base<<<(N_PATHS * NPACK + 255) / 256, 256, 0, stream>>>(cnt32, deg);
    k_scan<<<N_PATHS, 1024, 0, stream>>>(deg, rowptr);
    // software pipeline: scatter(p) overlaps gather(p-1)
    k_gs<<<SCAT_PP, 256, 0, stream>>>(-1, 0, edges, lrank, cnt32, rowptr, csr,
                                      (const float4*)el, (const float4*)er, feat, zbuf);
    k_gs<<<SCAT_PP + GATH_PP, 256, 0, stream>>>(0, 1, edges, lrank, cnt32, rowptr, csr,
                                      (const float4*)el, (const float4*)er, feat, zbuf);
    k_gs<<<SCAT_PP + GATH_PP, 256, 0, stream>>>(1, 2, edges, lrank, cnt32, rowptr, csr,
                                      (const float4*)el, (const float4*)er, feat, zbuf);
    k_gs<<<SCAT_PP + GATH_PP, 256, 0, stream>>>(2, -1, edges, lrank, cnt32, rowptr, csr,
                                      (const float4*)el, (const float4*)er, feat, zbuf);
    k_semout<<<N_NODES / 16, 256, 0, stream>>>(zbuf, w1T, b1, w2, out);
}

// Round 11
// 486.713 us; speedup vs baseline: 1.0631x; 1.0003x over previous
//
#include <hip/hip_runtime.h>
#include <hip/hip_bf16.h>
#include <hip/hip_fp16.h>

#define N_NODES 50000
#define N_EDGES 800000
#define N_PATHS 3
#define IN_F    128
#define HO      256   // H*OUT
#define N_HEADS 4
#define HID     128

#define BLK_PER_PATH 80
#define EDGES_PER_HB 10000                      // N_EDGES / BLK_PER_PATH
#define HIST_BLOCKS  (N_PATHS * BLK_PER_PATH)   // 240
#define PREP_BLOCKS  512                        // 384 fcwT + 128 w1T
#define NPACK        12500                      // N_NODES/4 packed u32
#define FEAT_RB      782                        // ceil(50000/64)
#define SCAT_BLOCKS  2344                       // 2.4M edges / (256*4)
#define FEAT_ELEMS   ((size_t)N_NODES * HO)

typedef __bf16 bf16;
typedef __bf16 bf16x8 __attribute__((ext_vector_type(8)));
typedef float  f32x4  __attribute__((ext_vector_type(4)));
typedef unsigned short u16;
typedef unsigned char  u8;
typedef unsigned int   u32;

// ---- prep role: fcwT[p][col][k] bf16 + w1T[col][k] bf16 --------------------
__device__ __forceinline__ void prep_role(int b, const float* __restrict__ fc_w,
                                          const float* __restrict__ w1,
                                          bf16* __restrict__ fcwT,
                                          bf16* __restrict__ w1T) {
    int g = b * 256 + threadIdx.x;
    if (g < N_PATHS * IN_F * HO) {                   // 98304: fc_w transpose
        int p = g >> 15, r = g & 32767;
        int col = r & 255, k = r >> 8;
        fcwT[(size_t)p * 32768 + col * IN_F + k] = (bf16)fc_w[(size_t)p * 32768 + k * HO + col];
    } else {
        int gg = g - N_PATHS * IN_F * HO;            // 32768: w1 transpose
        if (gg < HO * HID) {
            int k = gg & 255, j = gg >> 8;
            w1T[(size_t)j * HO + k] = (bf16)w1[(size_t)k * HID + j];
        }
    }
}

// ---- hist role: LDS histogram (4x u8 packed) + per-edge local rank ---------
__device__ __forceinline__ void hist_role(int b, const int* __restrict__ edges,
                                          u32* __restrict__ cnt32, u8* __restrict__ lrank,
                                          u32* hist) {
    const int p = b / BLK_PER_PATH, blk = b - p * BLK_PER_PATH;
    const int t = threadIdx.x;
    for (int i = t; i < NPACK; i += 256) hist[i] = 0;
    __syncthreads();

    const int* dstp = edges + (size_t)p * 2 * N_EDGES + N_EDGES + blk * EDGES_PER_HB;
    u8* lr = lrank + (size_t)p * N_EDGES + blk * EDGES_PER_HB;
    for (int q = t; q < EDGES_PER_HB / 4; q += 256) {
        int4 d4 = ((const int4*)dstp)[q];
        u32 o0 = atomicAdd(&hist[d4.x >> 2], 1u << ((d4.x & 3) * 8));
        u32 o1 = atomicAdd(&hist[d4.y >> 2], 1u << ((d4.y & 3) * 8));
        u32 o2 = atomicAdd(&hist[d4.z >> 2], 1u << ((d4.z & 3) * 8));
        u32 o3 = atomicAdd(&hist[d4.w >> 2], 1u << ((d4.w & 3) * 8));
        uchar4 r4;
        r4.x = (u8)(o0 >> ((d4.x & 3) * 8));
        r4.y = (u8)(o1 >> ((d4.y & 3) * 8));
        r4.z = (u8)(o2 >> ((d4.z & 3) * 8));
        r4.w = (u8)(o3 >> ((d4.w & 3) * 8));
        ((uchar4*)lr)[q] = r4;
    }
    __syncthreads();
    u32* out = cnt32 + (size_t)b * NPACK;
    for (int i = t; i < NPACK; i += 256) out[i] = hist[i];
}

// ---- fused: prep (trivial) + hist (LDS atomics) -----------------------------
__global__ __launch_bounds__(256) void k_ph(const float* __restrict__ fc_w,
                                            const float* __restrict__ w1,
                                            bf16* __restrict__ fcwT,
                                            bf16* __restrict__ w1T,
                                            const int* __restrict__ edges,
                                            u32* __restrict__ cnt32,
                                            u8* __restrict__ lrank) {
    __shared__ u32 hist[NPACK];                      // 50 KB
    const int bid = blockIdx.x;
    if (bid < PREP_BLOCKS)
        prep_role(bid, fc_w, w1, fcwT, w1T);
    else
        hist_role(bid - PREP_BLOCKS, edges, cnt32, lrank, hist);
}

// ---- base: per-node prefix over the 80 block counts (in place) + deg -------
__global__ __launch_bounds__(256) void k_base(u32* __restrict__ cnt32,
                                              int* __restrict__ deg) {
    int g = blockIdx.x * 256 + threadIdx.x;
    if (g >= N_PATHS * NPACK) return;
    int p = g / NPACK, q = g - p * NPACK;
    u32 s0 = 0, s1 = 0, s2 = 0, s3 = 0;
#pragma unroll 8
    for (int blk = 0; blk < BLK_PER_PATH; ++blk) {
        size_t idx = (size_t)(p * BLK_PER_PATH + blk) * NPACK + q;
        u32 c = cnt32[idx];
        cnt32[idx] = s0 | (s1 << 8) | (s2 << 16) | (s3 << 24);
        s0 += c & 0xff; s1 += (c >> 8) & 0xff; s2 += (c >> 16) & 0xff; s3 += c >> 24;
    }
    int4 d4 = {(int)s0, (int)s1, (int)s2, (int)s3};
    *(int4*)(deg + (size_t)p * N_NODES + 4 * q) = d4;
}

__global__ __launch_bounds__(1024) void k_scan(const int* __restrict__ deg,
                                               int* __restrict__ rowptr) {
    __shared__ int part[1024];
    const int p = blockIdx.x;
    const int* dg = deg + p * N_NODES;
    int* rp = rowptr + p * (N_NODES + 1);

    const int tid = threadIdx.x;
    const int CH = (N_NODES + 1023) / 1024;       // 49
    const int start = tid * CH;
    int s = 0;
    for (int i = 0; i < CH; ++i) { int idx = start + i; if (idx < N_NODES) s += dg[idx]; }
    part[tid] = s;
    __syncthreads();
    for (int off = 1; off < 1024; off <<= 1) {
        int v = (tid >= off) ? part[tid - off] : 0;
        __syncthreads();
        part[tid] += v;
        __syncthreads();
    }
    int excl = (tid == 0) ? 0 : part[tid - 1];
    for (int i = 0; i < CH; ++i) {
        int idx = start + i;
        if (idx < N_NODES) { rp[idx] = excl; excl += dg[idx]; }
    }
    if (tid == 1023) rp[N_NODES] = N_EDGES;
}

// ---- scatter role: all paths, 4 edges/thread, atomic-free ------------------
__device__ __forceinline__ void scatter_role(int b, const int* __restrict__ edges,
                                             const u8* __restrict__ lrank,
                                             const u32* __restrict__ cnt32,
                                             const int* __restrict__ rowptr,
                                             u16* __restrict__ csrAll) {
    int gt = b * 256 + threadIdx.x;
    if (gt >= (N_PATHS * N_EDGES) / 4) return;
    int base = gt * 4;
    int p = base / N_EDGES, e = base - p * N_EDGES;
    const int blk = e / EDGES_PER_HB;                // quad never crosses chunk
    const int* ep = edges + (size_t)p * 2 * N_EDGES;
    int4 s4 = *(const int4*)(ep + e);
    int4 d4 = *(const int4*)(ep + N_EDGES + e);
    uchar4 r4 = *(const uchar4*)(lrank + base);
    const int* rp = rowptr + p * (N_NODES + 1);
    const u32* bb = cnt32 + (size_t)(p * BLK_PER_PATH + blk) * NPACK;
    u16* c = csrAll + (size_t)p * N_EDGES;
    int p0 = rp[d4.x] + (int)((bb[d4.x >> 2] >> ((d4.x & 3) * 8)) & 0xff) + r4.x;
    int p1 = rp[d4.y] + (int)((bb[d4.y >> 2] >> ((d4.y & 3) * 8)) & 0xff) + r4.y;
    int p2 = rp[d4.z] + (int)((bb[d4.z >> 2] >> ((d4.z & 3) * 8)) & 0xff) + r4.z;
    int p3 = rp[d4.w] + (int)((bb[d4.w >> 2] >> ((d4.w & 3) * 8)) & 0xff) + r4.w;
    c[p0] = (u16)s4.x; c[p1] = (u16)s4.y; c[p2] = (u16)s4.z; c[p3] = (u16)s4.w;
}

// ---- fat feat role: one 64-row block does all 3 paths x 2 col-halves -------
__device__ __forceinline__ void feat_role(int rb, const float* __restrict__ h,
                                          const bf16* __restrict__ fcwT,
                                          const float* __restrict__ al,
                                          const float* __restrict__ ar,
                                          __half* __restrict__ featAll,
                                          float* __restrict__ elAll,
                                          float* __restrict__ erAll) {
    const int t = threadIdx.x, w = t >> 6, l = t & 63, lo = l & 15, hi = l >> 4;
    const int arow = rb * 64 + w * 16 + lo;
    const int crow = rb * 64 + w * 16 + hi * 4;

    bf16x8 afr[4];
    if (arow < N_NODES) {
        const float* hp = h + (size_t)arow * IN_F;
#pragma unroll
        for (int ks = 0; ks < 4; ++ks) {
            float4 f0 = *(const float4*)(hp + ks * 32 + hi * 8);
            float4 f1 = *(const float4*)(hp + ks * 32 + hi * 8 + 4);
            bf16x8 a;
            a[0]=(bf16)f0.x; a[1]=(bf16)f0.y; a[2]=(bf16)f0.z; a[3]=(bf16)f0.w;
            a[4]=(bf16)f1.x; a[5]=(bf16)f1.y; a[6]=(bf16)f1.z; a[7]=(bf16)f1.w;
            afr[ks] = a;
        }
    } else {
#pragma unroll
        for (int ks = 0; ks < 4; ++ks) { bf16x8 a = {}; afr[ks] = a; }
    }

    for (int p = 0; p < N_PATHS; ++p) {
        __half* feat = featAll + (size_t)p * FEAT_ELEMS;
        const float* alp = al + p * HO;
        const float* arp = ar + p * HO;
        float* elA = elAll + (size_t)p * N_NODES * 4;
        float* erA = erAll + (size_t)p * N_NODES * 4;
#pragma unroll
        for (int ch = 0; ch < 2; ++ch) {
            const bf16* W = fcwT + (size_t)p * 32768 + (size_t)ch * 128 * IN_F;
            f32x4 acc[8];
#pragma unroll
            for (int c = 0; c < 8; ++c) { f32x4 zz = {0.f,0.f,0.f,0.f}; acc[c] = zz; }
#pragma unroll
            for (int ctl = 0; ctl < 8; ++ctl) {
                const bf16* wp = W + (size_t)(ctl * 16 + lo) * IN_F + hi * 8;
                f32x4 a = acc[ctl];
#pragma unroll
                for (int ks = 0; ks < 4; ++ks)
                    a = __builtin_amdgcn_mfma_f32_16x16x32_bf16(afr[ks], *(const bf16x8*)(wp + ks * 32), a, 0, 0, 0);
                acc[ctl] = a;
            }
            float elP[2][4] = {{0}}, erP[2][4] = {{0}};
#pragma unroll
            for (int ctl = 0; ctl < 8; ++ctl) {
                const int gcol = ch * 128 + ctl * 16 + lo;
                const float av = alp[gcol], bv = arp[gcol];
                const int hl = ctl >> 2;
#pragma unroll
                for (int rr = 0; rr < 4; ++rr) {
                    float v = acc[ctl][rr];
                    elP[hl][rr] = fmaf(v, av, elP[hl][rr]);
                    erP[hl][rr] = fmaf(v, bv, erP[hl][rr]);
                    if (crow + rr < N_NODES)
                        feat[(size_t)(crow + rr) * HO + gcol] = __float2half(v);
                }
            }
#pragma unroll
            for (int hl = 0; hl < 2; ++hl)
#pragma unroll
                for (int rr = 0; rr < 4; ++rr) {
                    float v = elP[hl][rr], u = erP[hl][rr];
#pragma unroll
                    for (int m = 1; m <= 8; m <<= 1) {
                        v += __shfl_xor(v, m, 64);
                        u += __shfl_xor(u, m, 64);
                    }
                    elP[hl][rr] = v; erP[hl][rr] = u;
                }
            if (lo == 0) {
#pragma unroll
                for (int rr = 0; rr < 4; ++rr) {
                    if (crow + rr < N_NODES) {
                        *(float2*)&elA[(crow + rr) * 4 + ch * 2] = make_float2(elP[0][rr], elP[1][rr]);
                        *(float2*)&erA[(crow + rr) * 4 + ch * 2] = make_float2(erP[0][rr], erP[1][rr]);
                    }
                }
            }
        }
    }
}

// ---- fused: atomic-free scatter CONCURRENT with MFMA feat (no LDS!) --------
__global__ __launch_bounds__(256) void k_sf(const int* __restrict__ edges,
                                            const u8* __restrict__ lrank,
                                            const u32* __restrict__ cnt32,
                                            const int* __restrict__ rowptr,
                                            u16* __restrict__ csr,
                                            const float* __restrict__ h,
                                            const bf16* __restrict__ fcwT,
                                            const float* __restrict__ al,
                                            const float* __restrict__ ar,
                                            __half* __restrict__ featAll,
                                            float* __restrict__ elAll,
                                            float* __restrict__ erAll) {
    const int bid = blockIdx.x;
    if (bid < SCAT_BLOCKS)
        scatter_role(bid, edges, lrank, cnt32, rowptr, csr);
    else
        feat_role(bid - SCAT_BLOCKS, h, fcwT, al, ar, featAll, elAll, erAll);
}

// ---- gather: all paths, wave/node, SoA staging, unroll-8 -------------------
__global__ __launch_bounds__(256) void k_gather3(const u16* __restrict__ csrAll,
                                                 const int* __restrict__ rowptrAll,
                                                 const float4* __restrict__ elAll,
                                                 const float4* __restrict__ erAll,
                                                 const __half* __restrict__ featAll,
                                                 bf16* __restrict__ z) {
    __shared__ u32     s_off[4][64];
    __shared__ __half2 s_ad[4][4][66];
    const int pb = blockIdx.x;
    const int p  = pb / (N_NODES / 4);
    const int nb = pb - p * (N_NODES / 4);

    const int t = threadIdx.x, w = t >> 6, l = t & 63;
    const int half = l >> 5, c = l & 31, hh = c >> 3;
    const int n = nb * 4 + w;

    const u16*    csr    = csrAll + (size_t)p * N_EDGES;
    const int*    rowptr = rowptrAll + p * (N_NODES + 1);
    const float4* el4    = elAll + (size_t)p * N_NODES;
    const __half* feat   = featAll + (size_t)p * FEAT_ELEMS;

    const int b0 = rowptr[n], b1e = rowptr[n + 1];
    const float4 er_n = (erAll + (size_t)p * N_NODES)[n];

    __half2 acc0 = __float2half2_rn(0.f), acc1 = acc0, acc2 = acc0, acc3 = acc0;
    float4 den = {0.f, 0.f, 0.f, 0.f};

    for (int base = b0; base < b1e; base += 64) {
        const int cnt = min(64, b1e - base);
        if (l < cnt) {                               // staging: 2B csr + L2 el read
            int sv = csr[base + l];
            s_off[w][l] = (u32)(sv * HO);
            float4 e = el4[sv];
            float vx = e.x + er_n.x, vy = e.y + er_n.y,
                  vz = e.z + er_n.z, vw = e.w + er_n.w;
            vx = (vx >= 0.f) ? vx : 0.2f * vx;
            vy = (vy >= 0.f) ? vy : 0.2f * vy;
            vz = (vz >= 0.f) ? vz : 0.2f * vz;
            vw = (vw >= 0.f) ? vw : 0.2f * vw;
            float ex = __expf(vx), ey = __expf(vy), ez = __expf(vz), ew = __expf(vw);
            den.x += ex; den.y += ey; den.z += ez; den.w += ew;
            s_ad[w][0][l] = __float2half2_rn(ex);
            s_ad[w][1][l] = __float2half2_rn(ey);
            s_ad[w][2][l] = __float2half2_rn(ez);
            s_ad[w][3][l] = __float2half2_rn(ew);
        }
        int i2 = 0;
        for (; i2 + 8 <= cnt; i2 += 8) {             // 4 loads in flight per lane
            const int e0 = i2 + half, e1 = i2 + 2 + half,
                      e2 = i2 + 4 + half, e3 = i2 + 6 + half;
            u32 o0 = s_off[w][e0], o1 = s_off[w][e1], o2 = s_off[w][e2], o3 = s_off[w][e3];
            __half2 a0 = s_ad[w][hh][e0], a1 = s_ad[w][hh][e1],
                    a2 = s_ad[w][hh][e2], a3 = s_ad[w][hh][e3];
            const uint4 u0 = *(const uint4*)(feat + o0 + c * 8);
            const uint4 u1 = *(const uint4*)(feat + o1 + c * 8);
            const uint4 u2 = *(const uint4*)(feat + o2 + c * 8);
            const uint4 u3 = *(const uint4*)(feat + o3 + c * 8);
            acc0 = __hfma2(__builtin_bit_cast(__half2, u0.x), a0, acc0);
            acc1 = __hfma2(__builtin_bit_cast(__half2, u0.y), a0, acc1);
            acc2 = __hfma2(__builtin_bit_cast(__half2, u0.z), a0, acc2);
            acc3 = __hfma2(__builtin_bit_cast(__half2, u0.w), a0, acc3);
            acc0 = __hfma2(__builtin_bit_cast(__half2, u1.x), a1, acc0);
            acc1 = __hfma2(__builtin_bit_cast(__half2, u1.y), a1, acc1);
            acc2 = __hfma2(__builtin_bit_cast(__half2, u1.z), a1, acc2);
            acc3 = __hfma2(__builtin_bit_cast(__half2, u1.w), a1, acc3);
            acc0 = __hfma2(__builtin_bit_cast(__half2, u2.x), a2, acc0);
            acc1 = __hfma2(__builtin_bit_cast(__half2, u2.y), a2, acc1);
            acc2 = __hfma2(__builtin_bit_cast(__half2, u2.z), a2, acc2);
            acc3 = __hfma2(__builtin_bit_cast(__half2, u2.w), a2, acc3);
            acc0 = __hfma2(__builtin_bit_cast(__half2, u3.x), a3, acc0);
            acc1 = __hfma2(__builtin_bit_cast(__half2, u3.y), a3, acc1);
            acc2 = __hfma2(__builtin_bit_cast(__half2, u3.z), a3, acc2);
            acc3 = __hfma2(__builtin_bit_cast(__half2, u3.w), a3, acc3);
        }
        for (; i2 + 4 <= cnt; i2 += 4) {
            const int e0 = i2 + half, e1 = i2 + 2 + half;
            u32 o0 = s_off[w][e0], o1 = s_off[w][e1];
            __half2 a0 = s_ad[w][hh][e0], a1 = s_ad[w][hh][e1];
            const uint4 u0 = *(const uint4*)(feat + o0 + c * 8);
            const uint4 u1 = *(const uint4*)(feat + o1 + c * 8);
            acc0 = __hfma2(__builtin_bit_cast(__half2, u0.x), a0, acc0);
            acc1 = __hfma2(__builtin_bit_cast(__half2, u0.y), a0, acc1);
            acc2 = __hfma2(__builtin_bit_cast(__half2, u0.z), a0, acc2);
            acc3 = __hfma2(__builtin_bit_cast(__half2, u0.w), a0, acc3);
            acc0 = __hfma2(__builtin_bit_cast(__half2, u1.x), a1, acc0);
            acc1 = __hfma2(__builtin_bit_cast(__half2, u1.y), a1, acc1);
            acc2 = __hfma2(__builtin_bit_cast(__half2, u1.z), a1, acc2);
            acc3 = __hfma2(__builtin_bit_cast(__half2, u1.w), a1, acc3);
        }
        for (; i2 < cnt; i2 += 2) {
            const int e = i2 + half;
            if (e < cnt) {
                u32 o0 = s_off[w][e];
                __half2 a0 = s_ad[w][hh][e];
                const uint4 u = *(const uint4*)(feat + o0 + c * 8);
                acc0 = __hfma2(__builtin_bit_cast(__half2, u.x), a0, acc0);
                acc1 = __hfma2(__builtin_bit_cast(__half2, u.y), a0, acc1);
                acc2 = __hfma2(__builtin_bit_cast(__half2, u.z), a0, acc2);
                acc3 = __hfma2(__builtin_bit_cast(__half2, u.w), a0, acc3);
            }
        }
    }

    float s[8];
    { float2 f0 = __half22float2(acc0), f1 = __half22float2(acc1),
             f2 = __half22float2(acc2), f3 = __half22float2(acc3);
      s[0]=f0.x; s[1]=f0.y; s[2]=f1.x; s[3]=f1.y; s[4]=f2.x; s[5]=f2.y; s[6]=f3.x; s[7]=f3.y; }
#pragma unroll
    for (int j = 0; j < 8; ++j) s[j] += __shfl_xor(s[j], 32, 64);
#pragma unroll
    for (int off = 32; off; off >>= 1) {
        den.x += __shfl_xor(den.x, off, 64);
        den.y += __shfl_xor(den.y, off, 64);
        den.z += __shfl_xor(den.z, off, 64);
        den.w += __shfl_xor(den.w, off, 64);
    }
    const float d = (hh == 0) ? den.x : (hh == 1) ? den.y : (hh == 2) ? den.z : den.w;
    const float inv = (d > 0.f) ? 1.f / d : 0.f;
    if (half == 0) {
        bf16x8 ov;
#pragma unroll
        for (int j = 0; j < 8; ++j) {
            float v = s[j] * inv;
            v = (v > 0.f) ? v : expm1f(v);           // elu
            ov[j] = (bf16)v;
        }
        *(bf16x8*)(z + (size_t)n * (N_PATHS * HO) + p * HO + c * 8) = ov;
    }
}

// ---- semantic attention + output: bf16 LDS, MFMA logits (16 nodes/block) ---
__global__ __launch_bounds__(256) void k_semout(const bf16* __restrict__ z,
                                                const bf16* __restrict__ w1T,
                                                const float* __restrict__ b1,
                                                const float* __restrict__ w2,
                                                float* __restrict__ out) {
    __shared__ bf16  zs[48 * 264];
    __shared__ float psem[4][48];
    __shared__ float betas[16][4];

    const int t = threadIdx.x, w = t >> 6, l = t & 63;
    const int lo = l & 15, hi = l >> 4;
    const int n0 = blockIdx.x * 16;

    bf16x8 bfr[2][8];
#pragma unroll
    for (int ct = 0; ct < 2; ++ct) {
        const int j = (2 * w + ct) * 16 + lo;
#pragma unroll
        for (int s = 0; s < 8; ++s)
            bfr[ct][s] = *(const bf16x8*)(w1T + (size_t)j * HO + s * 32 + hi * 8);
    }

    const uint4* zg4 = (const uint4*)(z + (size_t)n0 * (N_PATHS * HO));
    for (int i = t; i < 1536; i += 256) {
        uint4 v = zg4[i];
        int r = i >> 5, cin = (i & 31) * 8;
        *(uint4*)&zs[r * 264 + cin] = v;
    }
    __syncthreads();

    f32x4 acc[2][3];
#pragma unroll
    for (int ct = 0; ct < 2; ++ct)
#pragma unroll
        for (int m = 0; m < 3; ++m) { f32x4 zz = {0.f,0.f,0.f,0.f}; acc[ct][m] = zz; }

    for (int s = 0; s < 8; ++s) {
#pragma unroll
        for (int m = 0; m < 3; ++m) {
            bf16x8 a = *(const bf16x8*)&zs[(m * 16 + lo) * 264 + s * 32 + hi * 8];
            acc[0][m] = __builtin_amdgcn_mfma_f32_16x16x32_bf16(a, bfr[0][s], acc[0][m], 0, 0, 0);
            acc[1][m] = __builtin_amdgcn_mfma_f32_16x16x32_bf16(a, bfr[1][s], acc[1][m], 0, 0, 0);
        }
    }

    const int j0 = (2 * w + 0) * 16 + lo;
    const int j1 = (2 * w + 1) * 16 + lo;
    const float b1_0 = b1[j0], w2_0 = w2[j0];
    const float b1_1 = b1[j1], w2_1 = w2[j1];
#pragma unroll
    for (int m = 0; m < 3; ++m) {
#pragma unroll
        for (int r = 0; r < 4; ++r) {
            float tt = tanhf(acc[0][m][r] + b1_0) * w2_0
                     + tanhf(acc[1][m][r] + b1_1) * w2_1;
            tt += __shfl_xor(tt, 1, 64);
            tt += __shfl_xor(tt, 2, 64);
            tt += __shfl_xor(tt, 4, 64);
            tt += __shfl_xor(tt, 8, 64);
            if (lo == 0) psem[w][m * 16 + hi * 4 + r] = tt;
        }
    }
    __syncthreads();
    if (t < 48) psem[0][t] = psem[0][t] + psem[1][t] + psem[2][t] + psem[3][t];
    __syncthreads();
    if (t < 16) {
        float a0 = psem[0][3 * t], a1 = psem[0][3 * t + 1], a2 = psem[0][3 * t + 2];
        float mx = fmaxf(a0, fmaxf(a1, a2));
        float e0 = __expf(a0 - mx), e1 = __expf(a1 - mx), e2 = __expf(a2 - mx);
        float is = 1.f / (e0 + e1 + e2);
        betas[t][0] = e0 * is; betas[t][1] = e1 * is; betas[t][2] = e2 * is;
    }
    __syncthreads();
    for (int i = 0; i < 16; ++i) {
        float bb0 = betas[i][0], bb1 = betas[i][1], bb2 = betas[i][2];
        float o = bb0 * (float)zs[(3 * i + 0) * 264 + t]
                + bb1 * (float)zs[(3 * i + 1) * 264 + t]
                + bb2 * (float)zs[(3 * i + 2) * 264 + t];
        out[(size_t)(n0 + i) * HO + t] = o;
    }
}

// ---------------------------------------------------------------------------
static inline size_t align256(size_t x) { return (x + 255) & ~(size_t)255; }

extern "C" void kernel_launch(void* const* d_in, const int* in_sizes, int n_in,
                              void* d_out, int out_size, void* d_ws, size_t ws_size,
                              hipStream_t stream) {
    const float* h     = (const float*)d_in[0];
    const int*   edges = (const int*)d_in[1];     // [P,2,E]
    const float* fc_w  = (const float*)d_in[2];   // [P,128,256]
    const float* al    = (const float*)d_in[3];   // [P,4,64]
    const float* ar    = (const float*)d_in[4];
    const float* w1    = (const float*)d_in[5];   // [256,128]
    const float* b1    = (const float*)d_in[6];   // [128]
    const float* w2    = (const float*)d_in[7];   // [128]
    float* out = (float*)d_out;

    char* base = (char*)d_ws;
    size_t off = 0;
    auto carve = [&](size_t bytes) -> char* {
        char* p = base + off; off = align256(off + bytes); return p;
    };
    __half* feat   = (__half*)carve((size_t)N_PATHS * FEAT_ELEMS * 2);   // 76.8 MB
    bf16*   zbuf   = (bf16*)carve((size_t)N_NODES * N_PATHS * HO * 2);   // 76.8 MB
    u16*    csr    = (u16*)carve((size_t)N_PATHS * N_EDGES * 2);         // 4.8 MB
    bf16*   fcwT   = (bf16*)carve((size_t)N_PATHS * IN_F * HO * 2);      // 192 KB
    bf16*   w1T    = (bf16*)carve((size_t)HO * HID * 2);                 // 64 KB
    float*  el     = (float*)carve((size_t)N_PATHS * N_NODES * 4 * 4);   // 2.4 MB
    float*  er     = (float*)carve((size_t)N_PATHS * N_NODES * 4 * 4);   // 2.4 MB
    int*    deg    = (int*)carve((size_t)N_PATHS * N_NODES * 4);         // 0.6 MB
    int*    rowptr = (int*)carve((size_t)N_PATHS * (N_NODES + 1) * 4);   // 0.6 MB
    u8*     lrank  = (u8*)carve((size_t)N_PATHS * N_EDGES);              // 2.4 MB
    u32*    cnt32  = (u32*)carve((size_t)HIST_BLOCKS * NPACK * 4);       // 12 MB
    (void)ws_size; (void)in_sizes; (void)n_in; (void)out_size;

    // prep (trivial) fused with widened hist (240 blocks, LDS atomics)
    k_ph<<<PREP_BLOCKS + HIST_BLOCKS, 256, 0, stream>>>(
        fc_w, w1, fcwT, w1T, edges, cnt32, lrank);
    k_base<<<(N_PATHS * NPACK + 255) / 256, 256, 0, stream>>>(cnt32, deg);
    k_scan<<<N_PATHS, 1024, 0, stream>>>(deg, rowptr);
    // atomic-free scatter concurrent with all 3 MFMA feat GEMMs (no LDS)
    k_sf<<<SCAT_BLOCKS + FEAT_RB, 256, 0, stream>>>(
        edges, lrank, cnt32, rowptr, csr, h, fcwT, al, ar, feat, el, er);
    // single-launch gather over all paths, unroll-8
    k_gather3<<<N_PATHS * (N_NODES / 4), 256, 0, stream>>>(
        csr, rowptr, (const float4*)el, (const float4*)er, feat, zbuf);
    k_semout<<<N_NODES / 16, 256, 0, stream>>>(zbuf, w1T, b1, w2, out);
}